// Round 1
// baseline (281.082 us; speedup 1.0000x reference)
//
#include <hip/hip_runtime.h>
#include <stdint.h>

// Encoder: out[n][0] = x[n]; out[n][1+i] = square(2*pi * x[n] * 2^i), i=0..14.
//
// Bit-exact replication of the f32 JAX reference:
//   t = RN32(f32(2pi) * x); p = t * 2^i (exact pow2 scale);
//   sq = fmodf(p, f32(2pi)) < f32(pi) ? +1 : -1.
// f32(2pi) = M*2^-21, f32(pi) = M*2^-22, M = 13176795 (same 24-bit mantissa).
// With t = mant*2^(E-23):  fmod(t*2^i, 2pif) < pif  <=>  floor(t*2^i/pif) even
//   <=>  bit (E-1+i) of the binary expansion of mant/M is 0.
// q = floor(mant*2^15 / M) (exact via magic multiply: err < 2^-24 < 1/M) holds
// those bits; q < 2^16, so clamping the shift to 31 yields bit=0 for any
// out-of-range index (covers x=0 / tiny x where E is very negative).
//
// R5: three structural deltas vs. the 6.1-TB/s fill kernel removed at once:
//   (1) whole-block fast path -> 8 stores with NO per-store guards (the
//       always-true `idx < nquarters` compares forced exec-mask churn around
//       every global_store_dwordx4 and blocked store clustering);
//   (2) x staged through LDS via one coalesced float2 load per thread
//       (was: 4-way duplicated sub-line wave loads interleaved with stores);
//   (3) compute all 8 float4 results into registers, then issue the 8
//       stores back-to-back (fill-kernel store burst pattern).
// Prediction: kernel ~60 -> ~50 us (dur_us ~277 -> ~267) if issue efficiency
// was the gap; neutral => kernel is at its effective floor (residual is fixed
// harness poison) and the answer is ROOFLINE.

typedef float v4f __attribute__((ext_vector_type(4)));
typedef float v2f __attribute__((ext_vector_type(2)));

constexpr int ITER = 8;   // quarter-rows (float4 stores) per thread
constexpr int BQ   = 256 * ITER;   // quarters per block (2048) = 512 rows

__global__ __launch_bounds__(256) void encoder_kernel(
    const float* __restrict__ x, float* __restrict__ out, int nquarters)
{
    __shared__ float lx[BQ / 4];                 // 512 floats = 2 KB

    const int t        = threadIdx.x;
    const int block_q0 = blockIdx.x * BQ;        // first quarter of this block
    const int row0     = block_q0 >> 2;          // first row of this block
    const bool full    = (block_q0 + BQ) <= nquarters;

    // ---- Stage x: one coalesced float2 per thread (512 floats/block). ----
    {
        const int r = 2 * t;
        if (full) {
            v2f v = *reinterpret_cast<const v2f*>(x + row0 + r);   // 8B aligned
            lx[r]     = v.x;
            lx[r + 1] = v.y;
        } else {
            lx[r]     = (block_q0 + 4 * r       < nquarters) ? x[row0 + r]     : 0.0f;
            lx[r + 1] = (block_q0 + 4 * (r + 1) < nquarters) ? x[row0 + r + 1] : 0.0f;
        }
    }
    __syncthreads();

    constexpr uint32_t M = 13176795u;                        // mantissa of f32(2pi)
    constexpr uint64_t G = 0xFFFFFFFFFFFFFFFFull / M + 1ull; // ceil(2^64/M)

    const int c0    = (t & 3) << 2;   // column group of this thread (const: 2048,256 are mult of 4)
    const int rbase = t >> 2;         // local row for j=0

    // ---- Compute all 8 result vectors into registers. ----
    v4f res[ITER];
    #pragma unroll
    for (int j = 0; j < ITER; ++j) {
        const float xj = lx[rbase + j * 64];     // 4-lane broadcast, conflict-free

        const float tv = 6.28318530717958647692f * xj;   // 0x40C90FDB * xj, RN
        const uint32_t bits = __float_as_uint(tv);
        const int      E    = (int)(bits >> 23) - 127;
        const uint32_t mant = (bits & 0x7FFFFFu) | 0x800000u;

        const uint32_t q    = (uint32_t)__umul64hi(((uint64_t)mant) << 15, G);
        const int      base = 16 - E;            // bit for col c: s = base-(c-1)

        v4f r;
        #pragma unroll
        for (int k = 0; k < 4; ++k) {
            const int c = c0 + k;
            if (c == 0) {
                r[k] = xj;                       // pass-through column
            } else {
                uint32_t s = (uint32_t)(base - (c - 1));
                s = s > 31u ? 31u : s;           // q < 2^16: clamp is safe
                r[k] = __uint_as_float(0x3F800000u | (((q >> s) & 1u) << 31)); // ±1.0f
            }
        }
        res[j] = r;
    }

    // ---- Back-to-back unguarded stores (fast path covers bench shape). ----
    if (full) {
        #pragma unroll
        for (int j = 0; j < ITER; ++j)
            reinterpret_cast<v4f*>(out)[block_q0 + t + j * 256] = res[j];
    } else {
        #pragma unroll
        for (int j = 0; j < ITER; ++j) {
            const int idx = block_q0 + t + j * 256;
            if (idx < nquarters)
                reinterpret_cast<v4f*>(out)[idx] = res[j];
        }
    }
}

extern "C" void kernel_launch(void* const* d_in, const int* in_sizes, int n_in,
                              void* d_out, int out_size, void* d_ws, size_t ws_size,
                              hipStream_t stream) {
    const float* x = (const float*)d_in[0];
    float* out = (float*)d_out;
    int nrows = in_sizes[0];                    // 4194304
    int nquarters = nrows * 4;                  // 16,777,216 float4 stores
    int blocks = (nquarters + BQ - 1) / BQ;     // 8192 exact at bench shape
    encoder_kernel<<<blocks, 256, 0, stream>>>(x, out, nquarters);
}